// Round 3
// baseline (267.790 us; speedup 1.0000x reference)
//
#include <hip/hip_runtime.h>
#include <cmath>

#define DIM 384
#define IMG 112
#define IMG2 (IMG*IMG)          // 12544
#define FINALN 16
#define PATCH 49
#define SPST 50
#define DROP_P 0.2f
#define NCG 32                  // pass-1 channel groups
#define CPG 12                  // channels per group (32*12 = 384)
#define PSLICE (FINALN*FINALN*PATCH)   // 12544 floats per (b,cg) slice

// ---------------- Pass 1: streaming logit partials ----------------
// 256 blocks = 8 b x 32 cg, 448 threads (7 waves). Each block streams 12
// contiguous channel planes (600 KB) with coalesced dwordx4 -> register
// partials -> LDS bijective scatter -> contiguous 50 KB slice of d_ws.
// hr is read EXACTLY once, fully coalesced: this is the HBM-facing pass.
__global__ __launch_bounds__(448) void kLogits(const float* __restrict__ hr,
                                               const float* __restrict__ aw,
                                               float* __restrict__ part) {
    __shared__ float sl[PSLICE];          // 50,176 B
    int t = threadIdx.x;
    int bidx = blockIdx.x;
    int b  = bidx >> 5;
    int cg = bidx & 31;
    int c0 = cg * CPG;

    const float* base = hr + (size_t)(b * DIM + c0) * IMG2;

    float acc[7][4];
    #pragma unroll
    for (int k = 0; k < 7; ++k) { acc[k][0]=acc[k][1]=acc[k][2]=acc[k][3]=0.f; }

    for (int c = 0; c < CPG; ++c) {
        float av = aw[c0 + c];            // wave-uniform -> scalar
        const float* pc = base + (size_t)c * IMG2;
        #pragma unroll
        for (int k = 0; k < 7; ++k) {
            int id = t + 448 * k;         // 3136 float4 = one 50-KB plane
            float4 v = *reinterpret_cast<const float4*>(pc + 4 * id);
            acc[k][0] = fmaf(v.x, av, acc[k][0]);
            acc[k][1] = fmaf(v.y, av, acc[k][1]);
            acc[k][2] = fmaf(v.z, av, acc[k][2]);
            acc[k][3] = fmaf(v.w, av, acc[k][3]);
        }
    }
    // scatter: id,e -> (r=id/28, col=4*(id%28)+e) -> (h,w,p); bijective since
    // patch stride 7 exactly tiles 112 = 16*7.
    #pragma unroll
    for (int k = 0; k < 7; ++k) {
        int id = t + 448 * k;
        int r = id / 28;
        int colq = id - r * 28;
        int h = r / 7, i = r - h * 7;
        #pragma unroll
        for (int e = 0; e < 4; ++e) {
            int col = colq * 4 + e;
            int w = col / 7, j = col - w * 7;
            sl[(h * FINALN + w) * PATCH + i * 7 + j] = acc[k][e];
        }
    }
    __syncthreads();
    float* dst = part + (size_t)bidx * PSLICE;
    #pragma unroll
    for (int k = 0; k < 7; ++k) {
        int id = t + 448 * k;
        *reinterpret_cast<float4*>(dst + 4 * id) =
            *reinterpret_cast<const float4*>(sl + 4 * id);
    }
}

// ---------------- Pass 2: softmax + weighted sum ----------------
// One block per patch. Patch loads issued EARLY (overlap logit gather +
// softmax) and hit L3 (pass 1 just streamed all of hr through it).
// No big LDS: occupancy is VGPR-bound, >=2 blocks/CU.
__global__ __launch_bounds__(512, 4) void kOut(const float* __restrict__ hr,
                                               const float* __restrict__ part,
                                               const float* __restrict__ du,
                                               const float* __restrict__ ab,
                                               const float* __restrict__ wmat,
                                               const float* __restrict__ bmat,
                                               float* __restrict__ out) {
    __shared__ float s_red[8 * PATCH];
    int tid = threadIdx.x;
    int id  = blockIdx.x;
    int nid = (id & 7) * 256 + (id >> 3);
    int b = nid >> 8, h = (nid >> 4) & 15, w = nid & 15;
    int hw = (h << 4) + w;

    // early-issue patch loads; consumed only after softmax (vmcnt overlaps)
    int g = tid >> 3, j = tid & 7;
    const float* gp = hr + (size_t)b * DIM * IMG2 + (size_t)(7 * h) * IMG + 7 * w
                    + (size_t)g * 6 * IMG2 + j;
    float v[42];
    if (j < 7) {
        #pragma unroll
        for (int it = 0; it < 42; ++it) {
            const int cc = it / 7, s = it % 7;
            v[it] = gp[(size_t)cc * IMG2 + s * IMG];
        }
    }

    float duv = 0.f, abv = 0.f, wv = 0.f, bv = 0.f;
    if (tid < 64) {
        if (tid < PATCH) { wv = wmat[tid]; bv = bmat[tid]; }
        duv = du[(b << 8) + hw];
        abv = ab[0];
    }

    // gather logit partials: threads 0..391, g2 = tid/49 sums 4 cg slices
    if (tid < 8 * PATCH) {
        int g2 = tid / PATCH, p = tid - g2 * PATCH;
        const float* pp = part + ((size_t)(b * NCG + g2 * 4)) * PSLICE
                        + (size_t)hw * PATCH + p;
        s_red[tid] = pp[0] + pp[PSLICE] + pp[2 * (size_t)PSLICE]
                   + pp[3 * (size_t)PSLICE];
    }
    __syncthreads();

    if (tid < 64) {
        float al = -1e30f;
        if (tid < PATCH) {
            float logit = abv;
            #pragma unroll
            for (int gg = 0; gg < 8; ++gg) logit += s_red[gg * PATCH + tid];
            float mask = (duv > DROP_P) ? 1.0f : 0.0f;
            al = fmaf(logit * mask, wv, bv);
        }
        float m = al;
        #pragma unroll
        for (int d = 32; d >= 1; d >>= 1) m = fmaxf(m, __shfl_xor(m, d, 64));
        float e = (tid < PATCH) ? __expf(al - m) : 0.f;
        float s = e;
        #pragma unroll
        for (int d = 32; d >= 1; d >>= 1) s += __shfl_xor(s, d, 64);
        if (tid < PATCH) s_red[tid] = e / s;   // attn
    }
    __syncthreads();

    // PV: lane (g,j) holds channels 6g..6g+5 at col j; reduce over j-lanes
    float att[7];
    int js = (j < 7) ? j : 0;
    #pragma unroll
    for (int s = 0; s < 7; ++s) att[s] = s_red[s * 7 + js];
    float oacc[6] = {0.f, 0.f, 0.f, 0.f, 0.f, 0.f};
    if (j < 7) {
        #pragma unroll
        for (int cc = 0; cc < 6; ++cc)
            #pragma unroll
            for (int s = 0; s < 7; ++s)
                oacc[cc] = fmaf(v[cc * 7 + s], att[s], oacc[cc]);
    }
    #pragma unroll
    for (int cc = 0; cc < 6; ++cc) {
        oacc[cc] += __shfl_xor(oacc[cc], 1, 64);
        oacc[cc] += __shfl_xor(oacc[cc], 2, 64);
        oacc[cc] += __shfl_xor(oacc[cc], 4, 64);
    }
    if (j == 0) {
        size_t ob = ((size_t)b * DIM + g * 6) * 256 + hw;
        #pragma unroll
        for (int cc = 0; cc < 6; ++cc) out[ob + (size_t)cc * 256] = oacc[cc];
    }
}

// ---------------- Fallback: proven single-pass kernel ----------------
__global__ __launch_bounds__(512, 4) void kFused(const float* __restrict__ hr,
                                                 const float* __restrict__ du,
                                                 const float* __restrict__ aw,
                                                 const float* __restrict__ ab,
                                                 const float* __restrict__ wmat,
                                                 const float* __restrict__ bmat,
                                                 float* __restrict__ out) {
    __shared__ float sp[DIM * SPST];
    __shared__ float s_red[8 * PATCH];
    int tid = threadIdx.x;
    int id  = blockIdx.x;
    int nid = (id & 7) * 256 + (id >> 3);
    int b = nid >> 8, h = (nid >> 4) & 15, w = nid & 15;
    float duv = 0.f, abv = 0.f, wv = 0.f, bv = 0.f;
    if (tid < 64) {
        if (tid < PATCH) { wv = wmat[tid]; bv = bmat[tid]; }
        duv = du[(b << 8) + (h << 4) + w];
        abv = ab[0];
    }
    int g = tid >> 3, j = tid & 7;
    const float* base = hr + (size_t)b * DIM * IMG2 + (size_t)(7 * h) * IMG + 7 * w;
    const float* gp = base + (size_t)g * 6 * IMG2 + j;
    float awr[6];
    #pragma unroll
    for (int cc = 0; cc < 6; ++cc) awr[cc] = aw[g * 6 + cc];
    float part[7] = {0.f, 0.f, 0.f, 0.f, 0.f, 0.f, 0.f};
    if (j < 7) {
        float v[42];
        #pragma unroll
        for (int it = 0; it < 42; ++it) {
            const int cc = it / 7, s = it % 7;
            v[it] = gp[(size_t)cc * IMG2 + s * IMG];
        }
        float* lp = sp + g * 6 * SPST + j;
        #pragma unroll
        for (int it = 0; it < 42; ++it) {
            const int cc = it / 7, s = it % 7;
            lp[cc * SPST + s * 7] = v[it];
            part[s] = fmaf(v[it], awr[cc], part[s]);
        }
    }
    #pragma unroll
    for (int s = 0; s < 7; ++s) {
        part[s] += __shfl_xor(part[s], 8, 64);
        part[s] += __shfl_xor(part[s], 16, 64);
        part[s] += __shfl_xor(part[s], 32, 64);
    }
    int wave = tid >> 6, lane = tid & 63;
    if (lane < 7) {
        #pragma unroll
        for (int s = 0; s < 7; ++s) s_red[wave * PATCH + s * 7 + lane] = part[s];
    }
    __syncthreads();
    if (tid < 64) {
        float al = -1e30f;
        if (tid < PATCH) {
            float logit = abv;
            #pragma unroll
            for (int gg = 0; gg < 8; ++gg) logit += s_red[gg * PATCH + tid];
            float mask = (duv > DROP_P) ? 1.0f : 0.0f;
            al = fmaf(logit * mask, wv, bv);
        }
        float m = al;
        #pragma unroll
        for (int d = 32; d >= 1; d >>= 1) m = fmaxf(m, __shfl_xor(m, d, 64));
        float e = (tid < PATCH) ? __expf(al - m) : 0.f;
        float s = e;
        #pragma unroll
        for (int d = 32; d >= 1; d >>= 1) s += __shfl_xor(s, d, 64);
        if (tid < PATCH) s_red[tid] = e / s;
    }
    __syncthreads();
    if (tid < DIM) {
        const float* pc = sp + tid * SPST;
        float acc = 0.f;
        #pragma unroll
        for (int k = 0; k < 24; ++k) {
            float2 v2 = *reinterpret_cast<const float2*>(pc + 2 * k);
            acc = fmaf(v2.x, s_red[2 * k], acc);
            acc = fmaf(v2.y, s_red[2 * k + 1], acc);
        }
        acc = fmaf(pc[48], s_red[48], acc);
        out[(((size_t)b * DIM + tid) * FINALN + h) * FINALN + w] = acc;
    }
}

extern "C" void kernel_launch(void* const* d_in, const int* in_sizes, int n_in,
                              void* d_out, int out_size, void* d_ws, size_t ws_size,
                              hipStream_t stream) {
    const float* hr   = (const float*)d_in[0];
    const float* du   = (const float*)d_in[2];
    const float* aw   = (const float*)d_in[3];
    const float* ab   = (const float*)d_in[4];
    const float* wmat = (const float*)d_in[5];
    const float* bmat = (const float*)d_in[6];
    float* out = (float*)d_out;

    size_t need = (size_t)8 * NCG * PSLICE * sizeof(float);  // 12.85 MB
    if (d_ws != nullptr && ws_size >= need) {
        float* part = (float*)d_ws;
        kLogits<<<256, 448, 0, stream>>>(hr, aw, part);
        kOut<<<2048, 512, 0, stream>>>(hr, part, du, ab, wmat, bmat, out);
    } else {
        kFused<<<2048, 512, 0, stream>>>(hr, du, aw, ab, wmat, bmat, out);
    }
}

// Round 4
// 242.088 us; speedup vs baseline: 1.1062x; 1.1062x over previous
//
#include <hip/hip_runtime.h>
#include <cmath>

#define DIM 384
#define IMG 112
#define IMG2 (IMG*IMG)          // 12544
#define FINALN 16
#define PATCH 49
#define DROP_P 0.2f

#define SLABC 64                // channels per sweep-2 chunk
#define SLABF (SLABC*392)       // 25088 floats = 100,352 B

// Block = (b, h, wh): 8 patches (w = 8wh..8wh+7), rows 7h..7h+6, cols 56wh..+55.
// 256 blocks x 512 threads, 1 block/CU (103.5 KB LDS).
// ALL global reads are aligned contiguous dwordx4 — the scattered 28-B patch
// gather (measured ~60us on its own, R3) is gone.
__global__ __launch_bounds__(512) void kRow(const float* __restrict__ hr,
                                            const float* __restrict__ du,
                                            const float* __restrict__ aw,
                                            const float* __restrict__ ab,
                                            const float* __restrict__ wmat,
                                            const float* __restrict__ bmat,
                                            float* __restrict__ out) {
    __shared__ float slab[SLABF];       // sweep-2 chunk; start reused for lacc
    __shared__ float s_aw[DIM];
    __shared__ float attn_s[8 * 50];    // stride 50: 8-lane broadcast, 8 banks

    int tid  = threadIdx.x;
    // pair-swizzle: blocks id and id+8 (same XCD under round-robin) become the
    // wh=0/1 halves of the same (b,h) row -> the straddled 64B line at col 56
    // is L2-shared instead of fetched twice.
    int id   = blockIdx.x;                // 0..255
    int nid  = (id & 7) * 32 + (id >> 3);
    int b  = nid >> 5;
    int h  = (nid >> 1) & 15;
    int wh = nid & 1;

    if (tid < DIM) s_aw[tid] = aw[tid];

    const float* base = hr + (size_t)b * DIM * IMG2 + (size_t)(7 * h) * IMG + 56 * wh;

    // ---- sweep 1: coalesced stream of all 384 channels -> register logits ----
    // thread t<392: c_sub = t/98 (4 channel phases), q = t%98 = fixed float4
    // slot (i = q/14 row, cq = q%14 col4). Accumulates over channels 4it+c_sub.
    int c_sub = tid / 98;
    int q     = tid - c_sub * 98;
    int i1 = q / 14, cq1 = q - i1 * 14;
    __syncthreads();                      // s_aw visible

    if (tid < 392) {
        const float* gp = base + (size_t)c_sub * IMG2 + i1 * IMG + 4 * cq1;
        float l0 = 0.f, l1 = 0.f, l2 = 0.f, l3 = 0.f;
        int awi = c_sub;
        #pragma unroll 8
        for (int it = 0; it < 96; ++it) {
            float4 v = *reinterpret_cast<const float4*>(gp);
            float av = s_aw[awi];
            l0 = fmaf(v.x, av, l0);
            l1 = fmaf(v.y, av, l1);
            l2 = fmaf(v.z, av, l2);
            l3 = fmaf(v.w, av, l3);
            gp += (size_t)4 * IMG2;
            awi += 4;
        }
        // lacc[c_sub][pos], stride 400 (b128-aligned), inside slab (free now)
        float4 st = make_float4(l0, l1, l2, l3);
        *reinterpret_cast<float4*>(&slab[c_sub * 400 + 4 * q]) = st;
    }
    __syncthreads();

    // ---- softmax: wave ww <-> patch w=ww; lane l<49 = patch position ----
    {
        int ww = tid >> 6, l = tid & 63;
        float al = -1e30f;
        if (l < PATCH) {
            int li = l / 7, lj = l - li * 7;
            int pos = li * 56 + 7 * ww + lj;
            float logit = slab[pos] + slab[400 + pos] + slab[800 + pos] + slab[1200 + pos];
            float duv  = du[(b << 8) + (h << 4) + (wh << 3) + ww];
            float mask = (duv > DROP_P) ? 1.0f : 0.0f;
            al = fmaf((logit + ab[0]) * mask, wmat[l], bmat[l]);
        }
        float m = al;
        #pragma unroll
        for (int d = 32; d >= 1; d >>= 1) m = fmaxf(m, __shfl_xor(m, d, 64));
        float e = (l < PATCH) ? __expf(al - m) : 0.f;
        float s = e;
        #pragma unroll
        for (int d = 32; d >= 1; d >>= 1) s += __shfl_xor(s, d, 64);
        if (l < PATCH) attn_s[ww * 50 + l] = e / s;
    }
    __syncthreads();

    // ---- sweep 2: 6 chunks x 64 channels, coalesced re-read (L3-hot) ----
    int wloc = tid & 7;                   // patch within block
    int cs   = tid >> 3;                  // channel within chunk (0..63)
    float attw[PATCH];
    #pragma unroll
    for (int p = 0; p < PATCH; ++p) attw[p] = attn_s[wloc * 50 + p];

    // stage offsets precomputed once; slab layout [c][392] == linear idx*4
    int goff[13], loff[13];
    #pragma unroll
    for (int k = 0; k < 13; ++k) {
        int idx = tid + 512 * k;
        int c = idx / 98, qq = idx - c * 98;
        int ii = qq / 14, cq = qq - ii * 14;
        goff[k] = c * IMG2 + ii * IMG + 4 * cq;
        loff[k] = idx * 4;
    }

    size_t ob = ((size_t)b * DIM + cs) * 256 + (h << 4) + (wh << 3) + wloc;

    for (int cc = 0; cc < 6; ++cc) {
        const float* cb = base + (size_t)(cc * SLABC) * IMG2;
        #pragma unroll
        for (int k = 0; k < 12; ++k)
            *reinterpret_cast<float4*>(&slab[loff[k]]) =
                *reinterpret_cast<const float4*>(cb + goff[k]);
        if (tid < 128)                    // 6272 = 12*512 + 128
            *reinterpret_cast<float4*>(&slab[loff[12]]) =
                *reinterpret_cast<const float4*>(cb + goff[12]);
        __syncthreads();

        // read map: lanes = 8 channels x 8 patches; stride 392 (mod 32 = 8)
        // with (8c,7w) lane pattern covers all 32 banks exactly 2-way = free.
        float o = 0.f;
        const float* sr = &slab[cs * 392 + 7 * wloc];
        #pragma unroll
        for (int p = 0; p < PATCH; ++p) {
            const int pi = p / 7, pj = p - (p / 7) * 7;
            o = fmaf(sr[pi * 56 + pj], attw[p], o);
        }
        out[ob + (size_t)(cc * SLABC) * 256] = o;
        if (cc < 5) __syncthreads();
    }
}

extern "C" void kernel_launch(void* const* d_in, const int* in_sizes, int n_in,
                              void* d_out, int out_size, void* d_ws, size_t ws_size,
                              hipStream_t stream) {
    const float* hr   = (const float*)d_in[0];
    // d_in[1] = guidance (unused by reference)
    const float* du   = (const float*)d_in[2];
    const float* aw   = (const float*)d_in[3];
    const float* ab   = (const float*)d_in[4];
    const float* wmat = (const float*)d_in[5];
    const float* bmat = (const float*)d_in[6];
    float* out = (float*)d_out;

    kRow<<<256, 512, 0, stream>>>(hr, du, aw, ab, wmat, bmat, out);
}

// Round 5
// 241.770 us; speedup vs baseline: 1.1076x; 1.0013x over previous
//
#include <hip/hip_runtime.h>
#include <hip/hip_fp16.h>
#include <cmath>

#define DIM 384
#define IMG 112
#define IMG2 (IMG*IMG)          // 12544
#define FINALN 16
#define PATCH 49
#define DROP_P 0.2f

// Block = (b, h, wh): 8 patches, rows 7h..7h+6, cols 56wh..56wh+55.
// 256 blocks x 512 threads, 1 block/CU.
// v5: hr is read EXACTLY ONCE (coalesced dwordx4). Values are held across the
// softmax barrier as packed fp16 in registers (192 half2/thread for t<392),
// then staged per-64-channel chunk into a 50-KB fp16 LDS slab for the PV
// reduction. Logits/attn stay full fp32 (identical path to the passing R4).
// fp16 only touches PV values: |out err| <= max|v|*2^-12 ~ 1.5e-3 < tol.
__global__ __launch_bounds__(512, 2) void kOnePass(const float* __restrict__ hr,
                                                   const float* __restrict__ du,
                                                   const float* __restrict__ aw,
                                                   const float* __restrict__ ab,
                                                   const float* __restrict__ wmat,
                                                   const float* __restrict__ bmat,
                                                   float* __restrict__ out) {
    __shared__ __half slabh[64 * 392];   // 50,176 B fp16 chunk (c-major, stride 392)
    __shared__ float s_aw[DIM];
    __shared__ float lacc[4 * 400];      // logit partials, stride 400 (b128 aligned)
    __shared__ float attn_s[8 * 50];     // per-patch attn, stride 50

    int tid = threadIdx.x;
    // XCD pair-swizzle: wh=0/1 halves of the same (b,h) row share an XCD L2.
    int id  = blockIdx.x;                 // 0..255
    int nid = (id & 7) * 32 + (id >> 3);
    int b  = nid >> 5;
    int h  = (nid >> 1) & 15;
    int wh = nid & 1;

    if (tid < DIM) s_aw[tid] = aw[tid];
    __syncthreads();

    const float* base = hr + (size_t)b * DIM * IMG2 + (size_t)(7 * h) * IMG + 56 * wh;

    // hold map (t < 392): c_sub = t/98 phase, q = t%98 fixed float4 slot
    // (row i1 = q/14, col4 = 4*(q%14)); channels c = 4k + c_sub, k = 0..95.
    int c_sub = tid / 98;
    int q     = tid - c_sub * 98;
    int i1 = q / 14, cq = q - i1 * 14;

    // ---- single coalesced sweep: fp32 logits + fp16 register retention ----
    __half2 hv[192];                      // 192 VGPRs of packed values
    if (tid < 392) {
        const float* gp = base + (size_t)c_sub * IMG2 + i1 * IMG + 4 * cq;
        float l0 = 0.f, l1 = 0.f, l2 = 0.f, l3 = 0.f;
        #pragma unroll
        for (int k = 0; k < 96; ++k) {    // full unroll: hv[] must stay in regs
            float4 v = *reinterpret_cast<const float4*>(gp + (size_t)(4 * k) * IMG2);
            float av = s_aw[4 * k + c_sub];
            l0 = fmaf(v.x, av, l0);
            l1 = fmaf(v.y, av, l1);
            l2 = fmaf(v.z, av, l2);
            l3 = fmaf(v.w, av, l3);
            hv[2 * k]     = __floats2half2_rn(v.x, v.y);
            hv[2 * k + 1] = __floats2half2_rn(v.z, v.w);
        }
        *reinterpret_cast<float4*>(&lacc[c_sub * 400 + 4 * q]) =
            make_float4(l0, l1, l2, l3);
    }
    __syncthreads();

    // ---- softmax: wave ww <-> patch, lane l < 49 = position (fp32, as R4) ----
    {
        int ww = tid >> 6, l = tid & 63;
        float al = -1e30f;
        if (l < PATCH) {
            int li = l / 7, lj = l - li * 7;
            int pos = li * 56 + 7 * ww + lj;
            float logit = lacc[pos] + lacc[400 + pos] + lacc[800 + pos] + lacc[1200 + pos];
            float duv  = du[(b << 8) + (h << 4) + (wh << 3) + ww];
            float mask = (duv > DROP_P) ? 1.0f : 0.0f;
            al = fmaf((logit + ab[0]) * mask, wmat[l], bmat[l]);
        }
        float m = al;
        #pragma unroll
        for (int d = 32; d >= 1; d >>= 1) m = fmaxf(m, __shfl_xor(m, d, 64));
        float e = (l < PATCH) ? __expf(al - m) : 0.f;
        float s = e;
        #pragma unroll
        for (int d = 32; d >= 1; d >>= 1) s += __shfl_xor(s, d, 64);
        if (l < PATCH) attn_s[ww * 50 + l] = e / s;
    }
    __syncthreads();

    // ---- PV: 6 chunks x 64 channels, staged from REGISTERS (no re-read) ----
    int wloc = tid & 7;                   // patch within block
    int cs   = tid >> 3;                  // channel within chunk (0..63)
    size_t ob = ((size_t)b * DIM + cs) * 256 + (h << 4) + (wh << 3) + wloc;

    float attw[PATCH];                    // loaded after chunk-0 staging frees hv regs

    for (int cc = 0; cc < 6; ++cc) {
        if (cc) __syncthreads();          // previous chunk's reads done
        if (tid < 392) {
            #pragma unroll
            for (int kk = 0; kk < 16; ++kk) {
                int c_local = 4 * kk + c_sub;         // row in chunk
                // 4 halves (positions 4q..4q+3) as one 8-B write, 8-B aligned
                *reinterpret_cast<uint2*>(&slabh[c_local * 392 + 4 * q]) =
                    *reinterpret_cast<const uint2*>(&hv[2 * (16 * cc + kk)]);
            }
        }
        __syncthreads();

        if (cc == 0) {                    // 32 hv regs freed -> attw fits now
            #pragma unroll
            for (int p = 0; p < PATCH; ++p) attw[p] = attn_s[wloc * 50 + p];
        }

        float o = 0.f;
        const __half* sr = &slabh[cs * 392 + 7 * wloc];
        #pragma unroll
        for (int p = 0; p < PATCH; ++p) {
            const int pi = p / 7, pj = p - pi * 7;
            o = fmaf(__half2float(sr[pi * 56 + pj]), attw[p], o);
        }
        out[ob + (size_t)(cc * 64) * 256] = o;
    }
}

extern "C" void kernel_launch(void* const* d_in, const int* in_sizes, int n_in,
                              void* d_out, int out_size, void* d_ws, size_t ws_size,
                              hipStream_t stream) {
    const float* hr   = (const float*)d_in[0];
    // d_in[1] = guidance (unused by reference)
    const float* du   = (const float*)d_in[2];
    const float* aw   = (const float*)d_in[3];
    const float* ab   = (const float*)d_in[4];
    const float* wmat = (const float*)d_in[5];
    const float* bmat = (const float*)d_in[6];
    float* out = (float*)d_out;

    kOnePass<<<256, 512, 0, stream>>>(hr, du, aw, ab, wmat, bmat, out);
}